// Round 2
// baseline (240.061 us; speedup 1.0000x reference)
//
#include <hip/hip_runtime.h>
#include <hip/hip_bf16.h>
#include <stdint.h>

#define IC 32
#define OC 32
#define NREG 33   // 32 hinges -> 33 piecewise-linear regions

typedef __attribute__((ext_vector_type(8))) short short8;
typedef __attribute__((ext_vector_type(4))) float f32x4;

static __device__ __forceinline__ short f2bf(float f) {
    __bf16 b = (__bf16)f;
    return __builtin_bit_cast(short, b);
}

// ===========================================================================
// Piecewise-linear machinery.
// h_k(t) = relu(t*w1[k] + b1[k]) is linear within regions bounded by hinges
// t_k = -b1[k]/w1[k]. region(t) = #{sorted hinges < t} (strict >; boundary
// terms are exactly 0 either way). Per-region:
//   edge:  W_r(t)[i,o] = P_r[i,o] + t*Q_r[i,o]
//   angle: f_r(t)[o]   = c_r[o]   + t*d_r[o]
// ===========================================================================

// --- sort hinges (rank sort, 32 elems) + active-set masks per region -------
__global__ void setup_sort(const float* __restrict__ eW1, const float* __restrict__ eb1,
                           const float* __restrict__ aW1, const float* __restrict__ ab1,
                           float* __restrict__ ehs, float* __restrict__ ahs,
                           unsigned* __restrict__ emask, unsigned* __restrict__ amask)
{
    __shared__ float hv[64];
    __shared__ float sv[64];
    __shared__ int   sk[64];
    int tid = threadIdx.x;
    {
        int k = tid & 31;
        float w = (tid < 32) ? eW1[k] : aW1[k];
        float b = (tid < 32) ? eb1[k] : ab1[k];
        hv[tid] = (w != 0.f) ? (-b / w) : 1e30f;   // w==0: no crossing
    }
    __syncthreads();
    {
        int grp = tid >> 5, k = tid & 31;
        float v = hv[tid];
        int rank = 0;
        for (int j = 0; j < 32; ++j) {
            float u = hv[grp * 32 + j];
            rank += (u < v) || (u == v && j < k);
        }
        sv[grp * 32 + rank] = v;
        sk[grp * 32 + rank] = k;
    }
    __syncthreads();
    if (tid < 32) ehs[tid] = sv[tid];
    else          ahs[tid - 32] = sv[tid - 32 + 32];
    if (tid == 0) {   // edge masks: active set walked across sorted hinges
        unsigned m = 0;
        for (int k = 0; k < 32; ++k) {
            float w = eW1[k], b = eb1[k];
            if (w < 0.f || (w == 0.f && b > 0.f)) m |= 1u << k;
        }
        emask[0] = m;
        for (int r = 1; r <= 32; ++r) {
            int k = sk[r - 1];
            float w = eW1[k];
            if (w > 0.f) m |= 1u << k; else if (w < 0.f) m &= ~(1u << k);
            emask[r] = m;
        }
    } else if (tid == 1) {
        unsigned m = 0;
        for (int k = 0; k < 32; ++k) {
            float w = aW1[k], b = ab1[k];
            if (w < 0.f || (w == 0.f && b > 0.f)) m |= 1u << k;
        }
        amask[0] = m;
        for (int r = 1; r <= 32; ++r) {
            int k = sk[32 + r - 1];
            float w = aW1[k];
            if (w > 0.f) m |= 1u << k; else if (w < 0.f) m &= ~(1u << k);
            amask[r] = m;
        }
    }
}

// --- per-region coefficient tables -----------------------------------------
// ePQ layout (bf16): [r][o][kk], kk<32 -> P_r[kk,o], kk>=32 -> Q_r[kk-32,o]
// so a lane's MFMA B-fragment (8 consecutive kk) is one 16B load.
// aCD layout (f32): [r][0..31]=c_r, [r][32..63]=d_r
__global__ __launch_bounds__(256) void setup_tables(
    const float* __restrict__ eW1, const float* __restrict__ eb1,
    const float* __restrict__ eW2, const float* __restrict__ eb2,
    const float* __restrict__ aW1, const float* __restrict__ ab1,
    const float* __restrict__ aW2, const float* __restrict__ ab2,
    const unsigned* __restrict__ emask, const unsigned* __restrict__ amask,
    __hip_bfloat16* __restrict__ ePQ, float* __restrict__ aCD)
{
    int b = blockIdx.x, tid = threadIdx.x;
    if (b < NREG) {
        unsigned m = emask[b];
        for (int pos = tid; pos < 1024; pos += 256) {   // pos = i*32+o
            int i = pos >> 5, o = pos & 31;
            float P = eb2[pos];
            float Q = 0.f;
            for (int k = 0; k < 32; ++k) {
                if (m & (1u << k)) {
                    float w2 = eW2[k * 1024 + pos];
                    P += eb1[k] * w2;
                    Q += eW1[k] * w2;
                }
            }
            ePQ[b * 2048 + o * 64 + i]      = (__hip_bfloat16)P;
            ePQ[b * 2048 + o * 64 + 32 + i] = (__hip_bfloat16)Q;
        }
    } else if (tid < 32) {
        int r = b - NREG, o = tid;
        unsigned m = amask[r];
        float c = ab2[o], d = 0.f;
        for (int k = 0; k < 32; ++k) {
            if (m & (1u << k)) {
                float w2 = aW2[k * 32 + o];
                c += ab1[k] * w2;
                d += aW1[k] * w2;
            }
        }
        aCD[r * 64 + o]      = c;
        aCD[r * 64 + 32 + o] = d;
    }
}

// --- edge bucketing: histogram -> scan -> scatter --------------------------
__global__ __launch_bounds__(256) void edge_hist(
    const float* __restrict__ edge_attr, const float* __restrict__ ehs,
    int* __restrict__ hist, int E)
{
    __shared__ float hs[32];
    __shared__ int lh[NREG];
    int tid = threadIdx.x;
    if (tid < 32) hs[tid] = ehs[tid];
    if (tid < NREG) lh[tid] = 0;
    __syncthreads();
    int e = blockIdx.x * 256 + tid;
    if (e < E) {
        float t = edge_attr[e];
        int r = 0;
#pragma unroll
        for (int j = 0; j < 32; ++j) r += (t > hs[j]) ? 1 : 0;
        atomicAdd(&lh[r], 1);
    }
    __syncthreads();
    if (tid < NREG && lh[tid] > 0) atomicAdd(&hist[tid], lh[tid]);
}

__global__ void scan_kernel(int* __restrict__ meta)   // meta: hist|starts|cursor
{
    if (threadIdx.x == 0) {
        const int* hist = meta;
        int* starts = meta + NREG;
        int s = 0;
        for (int r = 0; r < NREG; ++r) {
            starts[r] = s;
            s += (hist[r] + 15) & ~15;   // 16-align buckets -> tiles region-pure
        }
        starts[NREG] = s;
    }
}

__global__ __launch_bounds__(256) void edge_scatter(
    const float* __restrict__ edge_attr, const float* __restrict__ ehs,
    int* __restrict__ meta, int* __restrict__ sorted_idx, int E)
{
    __shared__ float hs[32];
    __shared__ int lh[NREG], lbase[NREG];
    int tid = threadIdx.x;
    if (tid < 32) hs[tid] = ehs[tid];
    if (tid < NREG) lh[tid] = 0;
    __syncthreads();
    int e = blockIdx.x * 256 + tid;
    int r = 0, myo = 0;
    if (e < E) {
        float t = edge_attr[e];
#pragma unroll
        for (int j = 0; j < 32; ++j) r += (t > hs[j]) ? 1 : 0;
        myo = atomicAdd(&lh[r], 1);
    }
    __syncthreads();
    if (tid < NREG) lbase[tid] = lh[tid] > 0 ? atomicAdd(&meta[2 * NREG + 1 + tid], lh[tid]) : 0;
    __syncthreads();
    if (e < E) sorted_idx[meta[NREG + r] + lbase[r] + myo] = e;
}

// --- edge GEMM: wave = 16 edges x 32 outputs, K=64 (x | t*x) ---------------
__global__ __launch_bounds__(256) void edge_gemm(
    const float* __restrict__ x, const int* __restrict__ edge_index,
    const float* __restrict__ edge_attr,
    const int* __restrict__ sorted_idx, const int* __restrict__ meta,
    const __hip_bfloat16* __restrict__ ePQ,
    float* __restrict__ out, int E, int maxTiles)
{
    int tid = threadIdx.x, lane = tid & 63;
    int tile = blockIdx.x * 4 + (tid >> 6);
    if (tile >= maxTiles) return;
    // region of this (region-pure) tile: search bucket table
    const int* hist = meta;
    const int* starts = meta + NREG;
    int base = tile * 16, r = -1;
    for (int rr = 0; rr < NREG; ++rr)
        if (base >= starts[rr] && base < starts[rr] + hist[rr]) r = rr;
    if (r < 0) return;   // padding-only tile

    int q = lane >> 4, l15 = lane & 15;
    const int kb = q * 8;
    const short* Tb = (const short*)ePQ + r * 2048;
    short8 B00 = *(const short8*)(Tb + l15 * 64 + kb);            // P, n=l15
    short8 B10 = *(const short8*)(Tb + l15 * 64 + 32 + kb);       // Q, n=l15
    short8 B01 = *(const short8*)(Tb + (16 + l15) * 64 + kb);     // P, n=16+l15
    short8 B11 = *(const short8*)(Tb + (16 + l15) * 64 + 32 + kb);// Q, n=16+l15

    int e = sorted_idx[tile * 16 + l15];
    int ec = e >= 0 ? e : 0;
    float t = edge_attr[ec];
    int col = edge_index[E + ec];                   // source node
    const float* xp = x + col * IC + kb;
    float4 xlo = *(const float4*)xp;
    float4 xhi = *(const float4*)(xp + 4);
    float xf[8] = {xlo.x, xlo.y, xlo.z, xlo.w, xhi.x, xhi.y, xhi.z, xhi.w};

    short8 a0, a1;
#pragma unroll
    for (int j = 0; j < 8; ++j) {
        a0[j] = f2bf(xf[j]);
        a1[j] = f2bf(t * xf[j]);
    }
    f32x4 z = {0.f, 0.f, 0.f, 0.f};
    f32x4 acc0 = __builtin_amdgcn_mfma_f32_16x16x32_bf16(a0, B00, z, 0, 0, 0);
    acc0 = __builtin_amdgcn_mfma_f32_16x16x32_bf16(a1, B10, acc0, 0, 0, 0);
    f32x4 acc1 = __builtin_amdgcn_mfma_f32_16x16x32_bf16(a0, B01, z, 0, 0, 0);
    acc1 = __builtin_amdgcn_mfma_f32_16x16x32_bf16(a1, B11, acc1, 0, 0, 0);

#pragma unroll
    for (int rr = 0; rr < 4; ++rr) {   // C row = q*4+rr (edge slot), col = n
        int e2 = sorted_idx[tile * 16 + q * 4 + rr];
        if (e2 >= 0) {
            int dst = edge_index[e2];               // destination node
            unsafeAtomicAdd(out + dst * OC + l15,      acc0[rr]);
            unsafeAtomicAdd(out + dst * OC + 16 + l15, acc1[rr]);
        }
    }
}

// --- angle branch: 2 atomics per angle ({cnt, sum_t} per node,region) ------
__global__ __launch_bounds__(256) void angle_count(
    const float* __restrict__ angles, const int* __restrict__ angle_index,
    const float* __restrict__ ahs, float* __restrict__ cnts, int A)
{
    __shared__ float hs[32];
    int tid = threadIdx.x;
    if (tid < 32) hs[tid] = ahs[tid];
    __syncthreads();
    int a = blockIdx.x * 256 + tid;
    if (a >= A) return;
    float t = angles[a];
    int r = 0;
#pragma unroll
    for (int j = 0; j < 32; ++j) r += (t > hs[j]) ? 1 : 0;
    int n = angle_index[A + a];                     // center node j
    float* p = cnts + ((size_t)n * NREG + r) * 2;
    unsafeAtomicAdd(p, 1.f);
    unsafeAtomicAdd(p + 1, t);
}

__global__ __launch_bounds__(256) void angle_combine(
    const float* __restrict__ cnts, const float* __restrict__ aCD,
    float* __restrict__ out, int N)
{
    __shared__ float cd[NREG * 64];
    int tid = threadIdx.x;
    for (int i = tid; i < NREG * 64; i += 256) cd[i] = aCD[i];
    __syncthreads();
    int node = blockIdx.x * 8 + (tid >> 5);
    if (node >= N) return;
    int o = tid & 31;
    const float* p = cnts + (size_t)node * NREG * 2;
    float acc = 0.f;
#pragma unroll
    for (int r = 0; r < NREG; ++r) {
        float2 cs = *(const float2*)(p + r * 2);
        acc += cs.x * cd[r * 64 + o] + cs.y * cd[r * 64 + 32 + o];
    }
    out[node * OC + o] += acc;
}

// ===========================================================================
// Fallback (round-1 kernels, known-good) if ws_size is too small
// ===========================================================================
__global__ __launch_bounds__(256) void edge_kernel_fb(
    const float* __restrict__ x, const int* __restrict__ edge_index,
    const float* __restrict__ edge_attr,
    const float* __restrict__ eW1, const float* __restrict__ eb1,
    const float* __restrict__ eW2, const float* __restrict__ eb2,
    float* __restrict__ out, int E)
{
    const int tid = threadIdx.x, lane = tid & 63;
    const int gwave = blockIdx.x * 4 + (tid >> 6);
    const int ot = gwave & 1, tile0 = gwave >> 1;
    const int tstride = (gridDim.x * 4) >> 1;
    const int q = lane >> 4, l15 = lane & 15, ocol = ot * 16 + l15;
    short8 Bf[33];
#pragma unroll
    for (int s = 0; s < 32; ++s) {
        short8 b;
#pragma unroll
        for (int j = 0; j < 8; ++j) b[j] = f2bf(eW2[s * 1024 + (q * 8 + j) * 32 + ocol]);
        Bf[s] = b;
    }
    {
        short8 b;
#pragma unroll
        for (int j = 0; j < 8; ++j) b[j] = f2bf(eb2[(q * 8 + j) * 32 + ocol]);
        Bf[32] = b;
    }
    const int numTiles = (E + 15) >> 4;
    for (int tile = tile0; tile < numTiles; tile += tstride) {
        const int e16 = tile << 4, eA = e16 + l15;
        const bool va = (eA < E);
        const int eAc = va ? eA : 0;
        const float t = va ? edge_attr[eAc] : 0.f;
        const int col = va ? edge_index[E + eAc] : 0;
        const float* xp = x + col * IC + q * 8;
        const float4 xlo = *(const float4*)(xp);
        const float4 xhi = *(const float4*)(xp + 4);
        float xf[8] = {xlo.x, xlo.y, xlo.z, xlo.w, xhi.x, xhi.y, xhi.z, xhi.w};
        f32x4 acc = {0.f, 0.f, 0.f, 0.f};
#pragma unroll
        for (int s = 0; s < 32; ++s) {
            float hs = t * eW1[s] + eb1[s];
            hs = hs > 0.f ? hs : 0.f;
            short8 a;
#pragma unroll
            for (int j = 0; j < 8; ++j) a[j] = f2bf(xf[j] * hs);
            acc = __builtin_amdgcn_mfma_f32_16x16x32_bf16(a, Bf[s], acc, 0, 0, 0);
        }
        {
            short8 a;
#pragma unroll
            for (int j = 0; j < 8; ++j) a[j] = f2bf(xf[j]);
            acc = __builtin_amdgcn_mfma_f32_16x16x32_bf16(a, Bf[32], acc, 0, 0, 0);
        }
        const int ebase = e16 + q * 4;
#pragma unroll
        for (int r = 0; r < 4; ++r) {
            const int er = ebase + r;
            if (er < E) unsafeAtomicAdd(out + edge_index[er] * OC + ocol, acc[r]);
        }
    }
}

__global__ __launch_bounds__(256) void angle_kernel_fb(
    const float* __restrict__ angles, const int* __restrict__ angle_index,
    const float* __restrict__ aW1, const float* __restrict__ ab1,
    const float* __restrict__ aW2, const float* __restrict__ ab2,
    float* __restrict__ out, int A)
{
    const int tid = threadIdx.x, lane = tid & 63;
    const int gwave = blockIdx.x * 4 + (tid >> 6);
    const int ot = gwave & 1, tile0 = gwave >> 1;
    const int tstride = (gridDim.x * 4) >> 1;
    const int q = lane >> 4, l15 = lane & 15, ocol = ot * 16 + l15;
    short8 Bf;
#pragma unroll
    for (int j = 0; j < 8; ++j) Bf[j] = f2bf(aW2[(q * 8 + j) * 32 + ocol]);
    const float bias = ab2[ocol];
    float w1[8], b1[8];
#pragma unroll
    for (int j = 0; j < 8; ++j) { w1[j] = aW1[q * 8 + j]; b1[j] = ab1[q * 8 + j]; }
    const int numTiles = (A + 15) >> 4;
    for (int tile = tile0; tile < numTiles; tile += tstride) {
        const int a16 = tile << 4, ai = a16 + l15;
        const float t = (ai < A) ? angles[ai] : 0.f;
        short8 a;
#pragma unroll
        for (int j = 0; j < 8; ++j) {
            float h = t * w1[j] + b1[j];
            h = h > 0.f ? h : 0.f;
            a[j] = f2bf(h);
        }
        f32x4 acc = {0.f, 0.f, 0.f, 0.f};
        acc = __builtin_amdgcn_mfma_f32_16x16x32_bf16(a, Bf, acc, 0, 0, 0);
        const int abase = a16 + q * 4;
#pragma unroll
        for (int r = 0; r < 4; ++r) {
            const int ar = abase + r;
            if (ar < A) unsafeAtomicAdd(out + angle_index[A + ar] * OC + ocol, acc[r] + bias);
        }
    }
}

// ===========================================================================
extern "C" void kernel_launch(void* const* d_in, const int* in_sizes, int n_in,
                              void* d_out, int out_size, void* d_ws, size_t ws_size,
                              hipStream_t stream)
{
    const float* x          = (const float*)d_in[0];
    const int*   edge_index = (const int*)d_in[1];
    const float* edge_attr  = (const float*)d_in[2];
    const int*   angle_index= (const int*)d_in[3];
    const float* angles     = (const float*)d_in[4];
    const float* eW1        = (const float*)d_in[5];
    const float* eb1        = (const float*)d_in[6];
    const float* eW2        = (const float*)d_in[7];
    const float* eb2        = (const float*)d_in[8];
    const float* aW1        = (const float*)d_in[9];
    const float* ab1        = (const float*)d_in[10];
    const float* aW2        = (const float*)d_in[11];
    const float* ab2        = (const float*)d_in[12];
    float* out = (float*)d_out;

    const int E = in_sizes[1] / 2;
    const int A = in_sizes[3] / 3;
    const int N = out_size / OC;
    const int maxTiles = (E + 15) / 16 + NREG;

    size_t off = 0;
    auto carve = [&](size_t bytes) {
        size_t o = off;
        off += (bytes + 255) & ~(size_t)255;
        return o;
    };
    char* w = (char*)d_ws;
    size_t o_ePQ   = carve((size_t)NREG * 2048 * 2);
    size_t o_aCD   = carve((size_t)NREG * 64 * 4);
    size_t o_ehs   = carve(128);
    size_t o_ahs   = carve(128);
    size_t o_emask = carve(NREG * 4);
    size_t o_amask = carve(NREG * 4);
    size_t o_meta  = carve((3 * NREG + 1) * 4);      // hist | starts(34) | cursor
    size_t o_sidx  = carve((size_t)maxTiles * 16 * 4);
    size_t o_cnts  = carve((size_t)N * NREG * 2 * 4);
    size_t needed = off;

    if (needed <= ws_size) {
        __hip_bfloat16* ePQ = (__hip_bfloat16*)(w + o_ePQ);
        float* aCD   = (float*)(w + o_aCD);
        float* ehs   = (float*)(w + o_ehs);
        float* ahs   = (float*)(w + o_ahs);
        unsigned* emask = (unsigned*)(w + o_emask);
        unsigned* amask = (unsigned*)(w + o_amask);
        int* meta    = (int*)(w + o_meta);
        int* sidx    = (int*)(w + o_sidx);
        float* cnts  = (float*)(w + o_cnts);

        hipMemsetAsync(d_out, 0, (size_t)out_size * 4, stream);
        hipMemsetAsync(meta, 0, (3 * NREG + 1) * 4, stream);
        hipMemsetAsync(sidx, 0xFF, (size_t)maxTiles * 16 * 4, stream);   // -1
        hipMemsetAsync(cnts, 0, (size_t)N * NREG * 2 * 4, stream);

        setup_sort<<<1, 64, 0, stream>>>(eW1, eb1, aW1, ab1, ehs, ahs, emask, amask);
        setup_tables<<<2 * NREG, 256, 0, stream>>>(eW1, eb1, eW2, eb2,
                                                   aW1, ab1, aW2, ab2,
                                                   emask, amask, ePQ, aCD);
        edge_hist<<<(E + 255) / 256, 256, 0, stream>>>(edge_attr, ehs, meta, E);
        scan_kernel<<<1, 64, 0, stream>>>(meta);
        edge_scatter<<<(E + 255) / 256, 256, 0, stream>>>(edge_attr, ehs, meta, sidx, E);
        edge_gemm<<<(maxTiles + 3) / 4, 256, 0, stream>>>(x, edge_index, edge_attr,
                                                          sidx, meta, ePQ, out, E, maxTiles);
        angle_count<<<(A + 255) / 256, 256, 0, stream>>>(angles, angle_index, ahs, cnts, A);
        angle_combine<<<(N + 7) / 8, 256, 0, stream>>>(cnts, aCD, out, N);
    } else {
        hipMemsetAsync(d_out, 0, (size_t)out_size * 4, stream);
        edge_kernel_fb<<<1024, 256, 0, stream>>>(x, edge_index, edge_attr,
                                                 eW1, eb1, eW2, eb2, out, E);
        angle_kernel_fb<<<1024, 256, 0, stream>>>(angles, angle_index,
                                                  aW1, ab1, aW2, ab2, out, A);
    }
}